// Round 1
// baseline (137.255 us; speedup 1.0000x reference)
//
#include <hip/hip_runtime.h>
#include <hip/hip_bf16.h>

// Problem constants
#define D_ 256
#define NROWS_Z 512      // 16*32 z frames
#define NROWS 528        // + 16 g rows
#define KQ 131072
#define NBLK 256         // k-chunk blocks for the big kernel
#define KC 512           // queue rows per block
#define SUBT 32          // 16-col subtiles per block (KC/16)
#define TAU_INV 14.285714285714286f

typedef __attribute__((ext_vector_type(8))) short short8;
typedef __attribute__((ext_vector_type(4))) float f32x4;

__device__ __forceinline__ short bf16r(float x) {
  union { float f; unsigned u; } c; c.f = x;
  unsigned r = (c.u + 0x7fffu + ((c.u >> 16) & 1u)) >> 16;  // RNE
  return (short)r;
}

// merge two (max, sumexp) partial-lse states
__device__ __forceinline__ void merge_ms(float& m, float& s, float m2, float s2) {
  float mm = fmaxf(m, m2);
  s = s * __expf(m - mm) + s2 * __expf(m2 - mm);
  m = mm;
}

// online lse update with one new value
__device__ __forceinline__ void online_update(float& m, float& s, float v) {
  float mn = fmaxf(m, v);
  s = s * __expf(m - mn) + __expf(v - mn);
  m = mn;
}

// ---------------- prep: A_bf16[528][256], rows pre-scaled by 1/tau ----------------
__global__ void prep_kernel(const float* __restrict__ z, const float* __restrict__ g,
                            short* __restrict__ Abf) {
  const int r = blockIdx.x, d = threadIdx.x;
  const float v = (r < NROWS_Z) ? z[r * D_ + d] : g[(r - NROWS_Z) * D_ + d];
  Abf[r * D_ + d] = bf16r(v * TAU_INV);
}

// ---------------- big: per-row online lse over the 131072 queue columns ----------------
// grid = 256 blocks (one 512-queue-row chunk each), block = 512 threads (8 waves).
// Each wave keeps A-fragments for 64 z-rows (4 slabs of 16) in registers; the
// 16 g-rows are done round-robin (wave == subtile&7) with A-frags from L2.
__global__ __launch_bounds__(512) void big_kernel(
    const float* __restrict__ queue, const short* __restrict__ Abf,
    float2* __restrict__ zpart, float2* __restrict__ gpart) {
  const int tid = threadIdx.x, blk = blockIdx.x;
  const int wid = tid >> 6, lane = tid & 63;
  const int l15 = lane & 15, l4 = lane >> 4;

  __shared__ __align__(16) char qs[16 * 512];   // 16 queue rows x 256 bf16, swizzled
  __shared__ float2 gbuf[8 * 16];

  // A fragments: row = l15 within slab, k = l4*8 + j, kstep covers d = k*32..k*32+31
  short8 afrag[4][8];
#pragma unroll
  for (int s = 0; s < 4; ++s) {
    const short* base = Abf + (wid * 64 + s * 16 + l15) * D_ + l4 * 8;
#pragma unroll
    for (int k = 0; k < 8; ++k) afrag[s][k] = *(const short8*)(base + k * 32);
  }
  const short* gbase = Abf + (NROWS_Z + l15) * D_ + l4 * 8;

  float mz[4][4], sz[4][4];
#pragma unroll
  for (int s = 0; s < 4; ++s)
#pragma unroll
    for (int r = 0; r < 4; ++r) { mz[s][r] = -1e30f; sz[s][r] = 0.f; }
  float mg[4], sg[4];
#pragma unroll
  for (int r = 0; r < 4; ++r) { mg[r] = -1e30f; sg[r] = 0.f; }

  const int srow = tid >> 5;           // staging: 32 threads per queue row
  const int sd0 = (tid & 31) * 8;      // 8 elems per thread
  const int woff = (srow * 512 + sd0 * 2) ^ ((srow & 7) << 4);

  for (int st = 0; st < SUBT; ++st) {
    const int k0 = blk * KC + st * 16;
    {
      const float* qp = queue + (size_t)(k0 + srow) * D_ + sd0;
      const float4 a = *(const float4*)qp;
      const float4 b = *(const float4*)(qp + 4);
      short8 v;
      v[0] = bf16r(a.x); v[1] = bf16r(a.y); v[2] = bf16r(a.z); v[3] = bf16r(a.w);
      v[4] = bf16r(b.x); v[5] = bf16r(b.y); v[6] = bf16r(b.z); v[7] = bf16r(b.w);
      *(short8*)(qs + woff) = v;
    }
    __syncthreads();

    const f32x4 fz = {0.f, 0.f, 0.f, 0.f};
    f32x4 acc[4];
#pragma unroll
    for (int s = 0; s < 4; ++s) acc[s] = fz;

#pragma unroll
    for (int k = 0; k < 8; ++k) {
      const int roff = (l15 * 512 + k * 64 + l4 * 16) ^ ((l15 & 7) << 4);
      const short8 bf = *(const short8*)(qs + roff);
#pragma unroll
      for (int s = 0; s < 4; ++s)
        acc[s] = __builtin_amdgcn_mfma_f32_16x16x32_bf16(afrag[s][k], bf, acc[s], 0, 0, 0);
    }
#pragma unroll
    for (int s = 0; s < 4; ++s)
#pragma unroll
      for (int r = 0; r < 4; ++r) online_update(mz[s][r], sz[s][r], acc[s][r]);

    // g-slab, round-robin across waves
    if ((st & 7) == wid) {
      f32x4 accg = fz;
#pragma unroll
      for (int k = 0; k < 8; ++k) {
        const int roff = (l15 * 512 + k * 64 + l4 * 16) ^ ((l15 & 7) << 4);
        const short8 bf = *(const short8*)(qs + roff);
        const short8 ag = *(const short8*)(gbase + k * 32);
        accg = __builtin_amdgcn_mfma_f32_16x16x32_bf16(ag, bf, accg, 0, 0, 0);
      }
#pragma unroll
      for (int r = 0; r < 4; ++r) online_update(mg[r], sg[r], accg[r]);
    }
    __syncthreads();
  }

  // merge (m,s) across the 16 column-lanes (xor masks 1,2,4,8 stay in l4-group)
#pragma unroll
  for (int s = 0; s < 4; ++s)
#pragma unroll
    for (int r = 0; r < 4; ++r) {
#pragma unroll
      for (int mask = 1; mask < 16; mask <<= 1) {
        const float om = __shfl_xor(mz[s][r], mask);
        const float os = __shfl_xor(sz[s][r], mask);
        merge_ms(mz[s][r], sz[s][r], om, os);
      }
    }
#pragma unroll
  for (int r = 0; r < 4; ++r) {
#pragma unroll
    for (int mask = 1; mask < 16; mask <<= 1) {
      const float om = __shfl_xor(mg[r], mask);
      const float os = __shfl_xor(sg[r], mask);
      merge_ms(mg[r], sg[r], om, os);
    }
  }

  if (l15 == 0) {
#pragma unroll
    for (int s = 0; s < 4; ++s)
#pragma unroll
      for (int r = 0; r < 4; ++r) {
        const int row = wid * 64 + s * 16 + l4 * 4 + r;
        zpart[row * NBLK + blk] = make_float2(mz[s][r], sz[s][r]);
      }
#pragma unroll
    for (int r = 0; r < 4; ++r)
      gbuf[wid * 16 + l4 * 4 + r] = make_float2(mg[r], sg[r]);
  }
  __syncthreads();
  if (tid < 16) {
    float m = gbuf[tid].x, s = gbuf[tid].y;
    for (int w = 1; w < 8; ++w) merge_ms(m, s, gbuf[w * 16 + tid].x, gbuf[w * 16 + tid].y);
    gpart[tid * NBLK + blk] = make_float2(m, s);
  }
}

// ---------------- zcol: masked lse over the 512 z columns + pos extraction ----------------
__global__ void zcol_kernel(const float* __restrict__ z, const float* __restrict__ g,
                            float2* __restrict__ zcol, float* __restrict__ posll,
                            float* __restrict__ posgl) {
  const int r = blockIdx.x, tid = threadIdx.x;
  __shared__ float rowv[D_];
  __shared__ float2 red[4];
  const float* src = (r < NROWS_Z) ? z + r * D_ : g + (r - NROWS_Z) * D_;
  rowv[tid] = src[tid] * TAU_INV;
  __syncthreads();

  float m = -1e30f, s = 0.f;
#pragma unroll
  for (int half = 0; half < 2; ++half) {
    const int c = tid + half * 256;
    const float4* zc = (const float4*)(z + (size_t)c * D_);
    float acc = 0.f;
    for (int d4 = 0; d4 < 64; ++d4) {
      const float4 q = zc[d4];
      acc += q.x * rowv[d4 * 4] + q.y * rowv[d4 * 4 + 1] +
             q.z * rowv[d4 * 4 + 2] + q.w * rowv[d4 * 4 + 3];
    }
    bool masked;
    if (r < NROWS_Z) {
      if (c == r + 1) posll[r] = acc;          // pos BEFORE masking (as in ref)
      masked = (c == r) || (c == r + 1);
    } else {
      const int b = r - NROWS_Z;
      if ((c >> 5) == b) posgl[c] = acc;       // c == b*32 + t
      masked = ((c >> 5) == b);
    }
    if (!masked) online_update(m, s, acc);
  }
#pragma unroll
  for (int mask = 1; mask < 64; mask <<= 1) {
    const float om = __shfl_xor(m, mask);
    const float os = __shfl_xor(s, mask);
    merge_ms(m, s, om, os);
  }
  if ((tid & 63) == 0) red[tid >> 6] = make_float2(m, s);
  __syncthreads();
  if (tid == 0) {
    for (int w = 1; w < 4; ++w) merge_ms(m, s, red[w].x, red[w].y);
    zcol[r] = make_float2(m, s);
  }
}

// ---------------- smooth ----------------
__global__ void smooth_kernel(const float* __restrict__ z, float* __restrict__ part) {
  const int tid = threadIdx.x;
  const int gid = blockIdx.x * 256 + tid;
  float acc = 0.f;
  for (int idx = gid; idx < 16 * 31 * 256; idx += 128 * 256) {
    const int d = idx & 255;
    const int bt = idx >> 8;
    const int b = bt / 31, t = bt - b * 31;
    const float dv = z[(b * 32 + t + 1) * 256 + d] - z[(b * 32 + t) * 256 + d];
    acc += dv * dv;
  }
  __shared__ float red[4];
#pragma unroll
  for (int mask = 1; mask < 64; mask <<= 1) acc += __shfl_xor(acc, mask);
  if ((tid & 63) == 0) red[tid >> 6] = acc;
  __syncthreads();
  if (tid == 0) part[blockIdx.x] = red[0] + red[1] + red[2] + red[3];
}

// ---------------- reduce: merge 256 chunk partials + zcol partial per row ----------------
__global__ void reduce_kernel(const float2* __restrict__ zpart, const float2* __restrict__ gpart,
                              const float2* __restrict__ zcol, float* __restrict__ lse_row) {
  const int r = blockIdx.x, tid = threadIdx.x;
  const float2 p = (r < NROWS_Z) ? zpart[r * NBLK + tid] : gpart[(r - NROWS_Z) * NBLK + tid];
  float m = p.x, s = p.y;
  __shared__ float2 red[4];
#pragma unroll
  for (int mask = 1; mask < 64; mask <<= 1) {
    const float om = __shfl_xor(m, mask);
    const float os = __shfl_xor(s, mask);
    merge_ms(m, s, om, os);
  }
  if ((tid & 63) == 0) red[tid >> 6] = make_float2(m, s);
  __syncthreads();
  if (tid == 0) {
    for (int w = 1; w < 4; ++w) merge_ms(m, s, red[w].x, red[w].y);
    const float2 zc = zcol[r];
    merge_ms(m, s, zc.x, zc.y);
    lse_row[r] = m + logf(s);
  }
}

// ---------------- final: losses ----------------
__global__ void final_kernel(const float* __restrict__ lse_row, const float* __restrict__ posll,
                             const float* __restrict__ posgl, const float* __restrict__ smoothp,
                             float* __restrict__ out) {
  const int tid = threadIdx.x;
  float a_ll = 0.f, a_gl = 0.f, a_sm = 0.f;
  for (int i = tid; i < 496; i += 256) {
    const int b = i / 31, t = i - b * 31;
    const int a = b * 32 + t;
    const float pos = posll[a], lse = lse_row[a];
    const float d = lse - pos;   // logaddexp(pos,lse) - pos, robust
    a_ll += (d > 0.f) ? d + log1pf(__expf(-d)) : log1pf(__expf(d));
  }
  for (int i = tid; i < 512; i += 256) {
    const float pos = posgl[i], lse = lse_row[NROWS_Z + (i >> 5)];
    const float d = lse - pos;
    a_gl += (d > 0.f) ? d + log1pf(__expf(-d)) : log1pf(__expf(d));
  }
  if (tid < 128) a_sm = smoothp[tid];

  __shared__ float red[4];
  float sums[3] = {a_ll, a_gl, a_sm};
  float tot[3];
  for (int j = 0; j < 3; ++j) {
    float v = sums[j];
#pragma unroll
    for (int mask = 1; mask < 64; mask <<= 1) v += __shfl_xor(v, mask);
    __syncthreads();
    if ((tid & 63) == 0) red[tid >> 6] = v;
    __syncthreads();
    tot[j] = red[0] + red[1] + red[2] + red[3];
  }
  if (tid == 0)
    out[0] = tot[0] / 496.f + 0.5f * (tot[1] / 512.f) + 0.1f * (tot[2] / 496.f);
}

extern "C" void kernel_launch(void* const* d_in, const int* in_sizes, int n_in,
                              void* d_out, int out_size, void* d_ws, size_t ws_size,
                              hipStream_t stream) {
  const float* z = (const float*)d_in[0];      // [512,256]
  const float* g = (const float*)d_in[1];      // [16,256]
  const float* queue = (const float*)d_in[3];  // [131072,256]
  float* out = (float*)d_out;
  char* ws = (char*)d_ws;

  constexpr size_t OFF_A = 0;                               // 528*256*2  = 270336
  constexpr size_t OFF_ZPART = OFF_A + 270336;              // 512*256*8  = 1048576
  constexpr size_t OFF_GPART = OFF_ZPART + 1048576;         // 16*256*8   = 32768
  constexpr size_t OFF_ZCOL = OFF_GPART + 32768;            // 528*8      = 4224
  constexpr size_t OFF_POSLL = OFF_ZCOL + 4224;             // 512*4      = 2048
  constexpr size_t OFF_POSGL = OFF_POSLL + 2048;            // 512*4      = 2048
  constexpr size_t OFF_SM = OFF_POSGL + 2048;               // 128*4      = 512
  constexpr size_t OFF_LSE = OFF_SM + 512;                  // 528*4      = 2112

  short* Abf = (short*)(ws + OFF_A);
  float2* zpart = (float2*)(ws + OFF_ZPART);
  float2* gpart = (float2*)(ws + OFF_GPART);
  float2* zcol = (float2*)(ws + OFF_ZCOL);
  float* posll = (float*)(ws + OFF_POSLL);
  float* posgl = (float*)(ws + OFF_POSGL);
  float* smoothp = (float*)(ws + OFF_SM);
  float* lse_row = (float*)(ws + OFF_LSE);

  prep_kernel<<<NROWS, 256, 0, stream>>>(z, g, Abf);
  big_kernel<<<NBLK, 512, 0, stream>>>(queue, Abf, zpart, gpart);
  zcol_kernel<<<NROWS, 256, 0, stream>>>(z, g, zcol, posll, posgl);
  smooth_kernel<<<128, 256, 0, stream>>>(z, smoothp);
  reduce_kernel<<<NROWS, 256, 0, stream>>>(zpart, gpart, zcol, lse_row);
  final_kernel<<<1, 256, 0, stream>>>(lse_row, posll, posgl, smoothp, out);
}

// Round 2
// 99.442 us; speedup vs baseline: 1.3803x; 1.3803x over previous
//
#include <hip/hip_runtime.h>
#include <hip/hip_bf16.h>

#define D_ 256
#define NROWS_Z 512
#define NROWS 528
#define KQ 131072
#define NBLK 256
#define KC 512
#define SUBT 32
// 1/tau * log2(e): logits computed directly in log2 domain
#define SCALE_A (14.285714285714286f * 1.4426950408889634f)
#define LN2 0.6931471805599453f

typedef __attribute__((ext_vector_type(8))) short short8;
typedef __attribute__((ext_vector_type(4))) float f32x4;

__device__ __forceinline__ float exp2fast(float x) {
  float r; asm("v_exp_f32 %0, %1" : "=v"(r) : "v"(x)); return r;
}
__device__ __forceinline__ float log2fast(float x) {
  float r; asm("v_log_f32 %0, %1" : "=v"(r) : "v"(x)); return r;
}

__device__ __forceinline__ short bf16r(float x) {
  union { float f; unsigned u; } c; c.f = x;
  unsigned r = (c.u + 0x7fffu + ((c.u >> 16) & 1u)) >> 16;  // RNE
  return (short)r;
}

// merge two (max, sum2^) lse states, log2 domain
__device__ __forceinline__ void merge_ms(float& m, float& s, float m2, float s2) {
  float mm = fmaxf(m, m2);
  s = s * exp2fast(m - mm) + s2 * exp2fast(m2 - mm);
  m = mm;
}

// defer-max online update (T13): 1 transcendental on the common path
__device__ __forceinline__ void upd(float& m, float& s, float v) {
  float d = v - m;
  if (d > 0.f) { s *= exp2fast(-d); m = v; d = 0.f; }
  s += exp2fast(d);
}

__device__ __forceinline__ short8 cvt8(float4 a, float4 b) {
  short8 v;
  v[0] = bf16r(a.x); v[1] = bf16r(a.y); v[2] = bf16r(a.z); v[3] = bf16r(a.w);
  v[4] = bf16r(b.x); v[5] = bf16r(b.y); v[6] = bf16r(b.z); v[7] = bf16r(b.w);
  return v;
}

// ---------------- prep: Abf[528][256] scaled (log2 domain), Zp[512][256] plain,
// ---------------- and per-row smoothness partials ----------------
__global__ void prep_kernel(const float* __restrict__ z, const float* __restrict__ g,
                            short* __restrict__ Abf, short* __restrict__ Zp,
                            float* __restrict__ smoothp) {
  const int r = blockIdx.x, d = threadIdx.x;
  const float v = (r < NROWS_Z) ? z[r * D_ + d] : g[(r - NROWS_Z) * D_ + d];
  Abf[r * D_ + d] = bf16r(v * SCALE_A);
  if (r < NROWS_Z) {
    Zp[r * D_ + d] = bf16r(v);
    float acc = 0.f;
    if ((r & 31) != 31) { const float dv = z[(r + 1) * D_ + d] - v; acc = dv * dv; }
#pragma unroll
    for (int mask = 1; mask < 64; mask <<= 1) acc += __shfl_xor(acc, mask);
    __shared__ float red[4];
    if ((d & 63) == 0) red[d >> 6] = acc;
    __syncthreads();
    if (d == 0) smoothp[r] = red[0] + red[1] + red[2] + red[3];
  }
}

// ---------------- big: per-row online lse over 131072 queue columns ----------------
// 256 blocks x 512 queue rows; 8 waves x 64 z-rows in registers; g rows round-robin.
// Double-buffered LDS, one barrier per subtile, defer-max lse, exp2 domain.
__global__ __launch_bounds__(512, 2) void big_kernel(
    const float* __restrict__ queue, const short* __restrict__ Abf,
    float2* __restrict__ zpart, float2* __restrict__ gpart) {
  const int tid = threadIdx.x, blk = blockIdx.x;
  const int wid = tid >> 6, lane = tid & 63;
  const int l15 = lane & 15, l4 = lane >> 4;

  __shared__ __align__(16) char qs[2][16 * 512];  // 2 x (16 rows x 256 bf16), swizzled
  __shared__ float2 gbuf[8 * 16];

  // A fragments resident: 4 slabs x 8 ksteps x 16B = 128 VGPR
  short8 afrag[4][8];
#pragma unroll
  for (int s = 0; s < 4; ++s) {
    const short* base = Abf + (wid * 64 + s * 16 + l15) * D_ + l4 * 8;
#pragma unroll
    for (int k = 0; k < 8; ++k) afrag[s][k] = *(const short8*)(base + k * 32);
  }
  const short* gbase = Abf + (NROWS_Z + l15) * D_ + l4 * 8;

  float mz[4][4], sz[4][4];
#pragma unroll
  for (int s = 0; s < 4; ++s)
#pragma unroll
    for (int r = 0; r < 4; ++r) { mz[s][r] = -1e30f; sz[s][r] = 0.f; }
  float mg[4], sg[4];
#pragma unroll
  for (int r = 0; r < 4; ++r) { mg[r] = -1e30f; sg[r] = 0.f; }

  const int srow = tid >> 5;       // 16 staging rows, 32 threads each
  const int sslot = tid & 31;      // 16B slot within row
  const int woff = srow * 512 + (((sslot ^ srow) & 31) << 4);
  const float* qbase = queue + (size_t)(blk * KC + srow) * D_ + sslot * 8;

  // prologue: stage subtile 0
  float4 pa = *(const float4*)qbase;
  float4 pb = *(const float4*)(qbase + 4);
  *(short8*)(qs[0] + woff) = cvt8(pa, pb);
  __syncthreads();

  for (int st = 0; st < SUBT; ++st) {
    const int cur = st & 1;
    if (st + 1 < SUBT) {           // issue next-tile global loads first
      const float* qp = qbase + (st + 1) * (16 * D_);
      pa = *(const float4*)qp;
      pb = *(const float4*)(qp + 4);
    }

    const f32x4 fz = {0.f, 0.f, 0.f, 0.f};
    f32x4 acc[4];
#pragma unroll
    for (int s = 0; s < 4; ++s) acc[s] = fz;

    const char* qb = qs[cur];
#pragma unroll
    for (int k = 0; k < 8; ++k) {
      const short8 bf = *(const short8*)(qb + l15 * 512 + ((((k * 4 + l4) ^ l15) & 31) << 4));
#pragma unroll
      for (int s = 0; s < 4; ++s)
        acc[s] = __builtin_amdgcn_mfma_f32_16x16x32_bf16(afrag[s][k], bf, acc[s], 0, 0, 0);
    }

    const bool gdo = ((st & 7) == wid);   // wave-uniform
    f32x4 accg = fz;
    if (gdo) {
#pragma unroll
      for (int k = 0; k < 8; ++k) {
        const short8 bf = *(const short8*)(qb + l15 * 512 + ((((k * 4 + l4) ^ l15) & 31) << 4));
        const short8 ag = *(const short8*)(gbase + k * 32);
        accg = __builtin_amdgcn_mfma_f32_16x16x32_bf16(ag, bf, accg, 0, 0, 0);
      }
    }

    if (st + 1 < SUBT)             // convert + write next tile (other buffer)
      *(short8*)(qs[cur ^ 1] + woff) = cvt8(pa, pb);

#pragma unroll
    for (int s = 0; s < 4; ++s)
#pragma unroll
      for (int r = 0; r < 4; ++r) upd(mz[s][r], sz[s][r], acc[s][r]);
    if (gdo) {
#pragma unroll
      for (int r = 0; r < 4; ++r) upd(mg[r], sg[r], accg[r]);
    }
    __syncthreads();
  }

  // merge across the 16 column-lanes
#pragma unroll
  for (int s = 0; s < 4; ++s)
#pragma unroll
    for (int r = 0; r < 4; ++r) {
#pragma unroll
      for (int mask = 1; mask < 16; mask <<= 1) {
        const float om = __shfl_xor(mz[s][r], mask);
        const float os = __shfl_xor(sz[s][r], mask);
        merge_ms(mz[s][r], sz[s][r], om, os);
      }
    }
#pragma unroll
  for (int r = 0; r < 4; ++r) {
#pragma unroll
    for (int mask = 1; mask < 16; mask <<= 1) {
      const float om = __shfl_xor(mg[r], mask);
      const float os = __shfl_xor(sg[r], mask);
      merge_ms(mg[r], sg[r], om, os);
    }
  }

  if (l15 == 0) {
#pragma unroll
    for (int s = 0; s < 4; ++s)
#pragma unroll
      for (int r = 0; r < 4; ++r) {
        const int row = wid * 64 + s * 16 + l4 * 4 + r;
        zpart[row * NBLK + blk] = make_float2(mz[s][r], sz[s][r]);
      }
#pragma unroll
    for (int r = 0; r < 4; ++r)
      gbuf[wid * 16 + l4 * 4 + r] = make_float2(mg[r], sg[r]);
  }
  __syncthreads();
  if (tid < 16) {
    float m = gbuf[tid].x, s = gbuf[tid].y;
    for (int w = 1; w < 8; ++w) merge_ms(m, s, gbuf[w * 16 + tid].x, gbuf[w * 16 + tid].y);
    gpart[tid * NBLK + blk] = make_float2(m, s);
  }
}

// ---------------- zmm: masked lse over the 512 z columns via MFMA + pos extraction ----
// 33 blocks x 16 rows; 8 waves x 64 cols each.
__global__ __launch_bounds__(512) void zmm_kernel(
    const short* __restrict__ Abf, const short* __restrict__ Zp,
    float2* __restrict__ zcol, float* __restrict__ posll, float* __restrict__ posgl) {
  const int tid = threadIdx.x;
  const int wid = tid >> 6, lane = tid & 63;
  const int l15 = lane & 15, l4 = lane >> 4;
  const int r0 = blockIdx.x * 16;

  short8 af[8];
#pragma unroll
  for (int k = 0; k < 8; ++k)
    af[k] = *(const short8*)(Abf + (r0 + l15) * D_ + l4 * 8 + k * 32);

  float m[4], s[4];
#pragma unroll
  for (int r = 0; r < 4; ++r) { m[r] = -1e30f; s[r] = 0.f; }

  for (int st = 0; st < 4; ++st) {
    const int c0 = wid * 64 + st * 16;
    const f32x4 fz = {0.f, 0.f, 0.f, 0.f};
    f32x4 acc = fz;
#pragma unroll
    for (int k = 0; k < 8; ++k) {
      const short8 bq = *(const short8*)(Zp + (c0 + l15) * D_ + l4 * 8 + k * 32);
      acc = __builtin_amdgcn_mfma_f32_16x16x32_bf16(af[k], bq, acc, 0, 0, 0);
    }
#pragma unroll
    for (int r = 0; r < 4; ++r) {
      const int row = r0 + l4 * 4 + r;
      const int col = c0 + l15;
      const float v = acc[r];
      bool masked;
      if (r0 < NROWS_Z) {
        if (col == row + 1) posll[row] = v * LN2;
        masked = (col == row) || (col == row + 1);
      } else {
        const int b = row - NROWS_Z;
        const bool own = ((col >> 5) == b);
        if (own) posgl[col] = v * LN2;
        masked = own;
      }
      if (!masked) upd(m[r], s[r], v);
    }
  }
#pragma unroll
  for (int r = 0; r < 4; ++r) {
#pragma unroll
    for (int mask = 1; mask < 16; mask <<= 1) {
      const float om = __shfl_xor(m[r], mask);
      const float os = __shfl_xor(s[r], mask);
      merge_ms(m[r], s[r], om, os);
    }
  }
  __shared__ float2 lds[8][16];
  if (l15 == 0) {
#pragma unroll
    for (int r = 0; r < 4; ++r) lds[wid][l4 * 4 + r] = make_float2(m[r], s[r]);
  }
  __syncthreads();
  if (tid < 16) {
    float mm = lds[0][tid].x, ss = lds[0][tid].y;
    for (int w = 1; w < 8; ++w) merge_ms(mm, ss, lds[w][tid].x, lds[w][tid].y);
    zcol[r0 + tid] = make_float2(mm, ss);
  }
}

// ---------------- reduce: merge 256 chunk partials + zcol partial per row ----------------
__global__ void reduce_kernel(const float2* __restrict__ zpart, const float2* __restrict__ gpart,
                              const float2* __restrict__ zcol, float* __restrict__ lse_row) {
  const int r = blockIdx.x, tid = threadIdx.x;
  const float2 p = (r < NROWS_Z) ? zpart[r * NBLK + tid] : gpart[(r - NROWS_Z) * NBLK + tid];
  float m = p.x, s = p.y;
  __shared__ float2 red[4];
#pragma unroll
  for (int mask = 1; mask < 64; mask <<= 1) {
    const float om = __shfl_xor(m, mask);
    const float os = __shfl_xor(s, mask);
    merge_ms(m, s, om, os);
  }
  if ((tid & 63) == 0) red[tid >> 6] = make_float2(m, s);
  __syncthreads();
  if (tid == 0) {
    for (int w = 1; w < 4; ++w) merge_ms(m, s, red[w].x, red[w].y);
    const float2 zc = zcol[r];
    merge_ms(m, s, zc.x, zc.y);
    lse_row[r] = LN2 * (m + log2fast(s));   // back to natural log
  }
}

// ---------------- final: losses ----------------
__global__ void final_kernel(const float* __restrict__ lse_row, const float* __restrict__ posll,
                             const float* __restrict__ posgl, const float* __restrict__ smoothp,
                             float* __restrict__ out) {
  const int tid = threadIdx.x;
  float a_ll = 0.f, a_gl = 0.f, a_sm = 0.f;
  for (int i = tid; i < 496; i += 256) {
    const int b = i / 31, t = i - b * 31;
    const int a = b * 32 + t;
    const float pos = posll[a], lse = lse_row[a];
    const float d = lse - pos;
    a_ll += (d > 0.f) ? d + log1pf(__expf(-d)) : log1pf(__expf(d));
  }
  for (int i = tid; i < 512; i += 256) {
    const float pos = posgl[i], lse = lse_row[NROWS_Z + (i >> 5)];
    const float d = lse - pos;
    a_gl += (d > 0.f) ? d + log1pf(__expf(-d)) : log1pf(__expf(d));
  }
  for (int i = tid; i < 512; i += 256) a_sm += smoothp[i];

  __shared__ float red[4];
  float sums[3] = {a_ll, a_gl, a_sm};
  float tot[3];
  for (int j = 0; j < 3; ++j) {
    float v = sums[j];
#pragma unroll
    for (int mask = 1; mask < 64; mask <<= 1) v += __shfl_xor(v, mask);
    __syncthreads();
    if ((tid & 63) == 0) red[tid >> 6] = v;
    __syncthreads();
    tot[j] = red[0] + red[1] + red[2] + red[3];
  }
  if (tid == 0)
    out[0] = tot[0] / 496.f + 0.5f * (tot[1] / 512.f) + 0.1f * (tot[2] / 496.f);
}

extern "C" void kernel_launch(void* const* d_in, const int* in_sizes, int n_in,
                              void* d_out, int out_size, void* d_ws, size_t ws_size,
                              hipStream_t stream) {
  const float* z = (const float*)d_in[0];      // [512,256]
  const float* g = (const float*)d_in[1];      // [16,256]
  const float* queue = (const float*)d_in[3];  // [131072,256]
  float* out = (float*)d_out;
  char* ws = (char*)d_ws;

  constexpr size_t OFF_A = 0;                         // 528*256*2 = 270336
  constexpr size_t OFF_ZP = OFF_A + 270336;           // 512*256*2 = 262144
  constexpr size_t OFF_ZPART = OFF_ZP + 262144;       // 512*256*8 = 1048576
  constexpr size_t OFF_GPART = OFF_ZPART + 1048576;   // 16*256*8  = 32768
  constexpr size_t OFF_ZCOL = OFF_GPART + 32768;      // 528*8     = 4224
  constexpr size_t OFF_POSLL = OFF_ZCOL + 4224;       // 512*4
  constexpr size_t OFF_POSGL = OFF_POSLL + 2048;      // 512*4
  constexpr size_t OFF_SM = OFF_POSGL + 2048;         // 512*4
  constexpr size_t OFF_LSE = OFF_SM + 2048;           // 528*4

  short* Abf = (short*)(ws + OFF_A);
  short* Zp = (short*)(ws + OFF_ZP);
  float2* zpart = (float2*)(ws + OFF_ZPART);
  float2* gpart = (float2*)(ws + OFF_GPART);
  float2* zcol = (float2*)(ws + OFF_ZCOL);
  float* posll = (float*)(ws + OFF_POSLL);
  float* posgl = (float*)(ws + OFF_POSGL);
  float* smoothp = (float*)(ws + OFF_SM);
  float* lse_row = (float*)(ws + OFF_LSE);

  prep_kernel<<<NROWS, 256, 0, stream>>>(z, g, Abf, Zp, smoothp);
  big_kernel<<<NBLK, 512, 0, stream>>>(queue, Abf, zpart, gpart);
  zmm_kernel<<<33, 512, 0, stream>>>(Abf, Zp, zcol, posll, posgl);
  reduce_kernel<<<NROWS, 256, 0, stream>>>(zpart, gpart, zcol, lse_row);
  final_kernel<<<1, 256, 0, stream>>>(lse_row, posll, posgl, smoothp, out);
}